// Round 14
// baseline (2354.720 us; speedup 1.0000x reference)
//
#include <hip/hip_runtime.h>
#include <math.h>

typedef float  v4f   __attribute__((ext_vector_type(4)));
typedef double v2d   __attribute__((ext_vector_type(2)));
typedef double v4d   __attribute__((ext_vector_type(4)));
typedef float  f32x4 __attribute__((ext_vector_type(4)));
typedef short  s16x8 __attribute__((ext_vector_type(8)));

#define NB   16384
#define KCTX 1284
#define CSL  (KCTX/4)    // 321 float4 per ctx row

// ---- fp64 MFMA: D[16x16] += A[16x4] * B[4x16], per-wave ----
#if defined(__has_builtin)
#  if __has_builtin(__builtin_amdgcn_mfma_f64_16x16x4f64)
#    define MFMA64(a, b, c) __builtin_amdgcn_mfma_f64_16x16x4f64((a), (b), (c), 0, 0, 0)
#  endif
#endif
#ifndef MFMA64
static __device__ __forceinline__ v4d mfma64_asm(double a, double b, v4d c) {
  asm volatile("v_mfma_f64_16x16x4_f64 %0, %1, %2, %0" : "+v"(c) : "v"(a), "v"(b));
  return c;
}
#  define MFMA64(a, b, c) mfma64_asm((a), (b), (c))
#endif

// ---- bf16 MFMA 16x16x32 (inline asm, volatile; r11/r13-proven) ----
static __device__ __forceinline__ f32x4 mfma_bf16(s16x8 a, s16x8 b, f32x4 c) {
  asm volatile("v_mfma_f32_16x16x32_bf16 %0, %1, %2, %0" : "+v"(c) : "v"(a), "v"(b));
  return c;
}
// MFMA-dst -> VALU-read hazard guard (r11-proven form)
#define MFMA_GUARD() do {                                  \
  __builtin_amdgcn_sched_barrier(0);                       \
  asm volatile("s_nop 7\ns_nop 7\ns_nop 7\ns_nop 7");      \
  __builtin_amdgcn_sched_barrier(0);                       \
} while (0)

__device__ __forceinline__ unsigned long long f64_ord(double f) {
  unsigned long long u = (unsigned long long)__double_as_longlong(f);
  return (u & 0x8000000000000000ull) ? ~u : (u | 0x8000000000000000ull);
}

// ---------------- fused prep: ctx concat + 6 weight splits + kpk zero -------
// ranges (item counts, 256/block, total = 9,035,776 = 35,296 blocks exactly)
#define CT_ITEMS  (NB * CSL)          // 5,259,264 float4 slots
#define E_C11     (1024 * 1312)
#define E_C12     (1024 * 1024)
#define E_C21     ( 512 * 1312)
#define E_C22     ( 512 *  512)
#define E_C31     ( 256 * 1312)
#define E_C32     ( 256 *  256)
#define KPK_ITEMS (3 * NB)

static __device__ __forceinline__ void split_one(
    const float* __restrict__ W, unsigned short* __restrict__ out,
    int N, int K, int KP, int idx)
{
  size_t total = (size_t)N * KP;
  int n = idx / KP, k = idx - n * KP;
  float v = (k < K) ? W[(size_t)n * K + k] : 0.f;
  unsigned u1 = __float_as_uint(v);
  float f1 = __uint_as_float(u1 & 0xFFFF0000u);
  float r1 = v - f1;
  unsigned u2 = __float_as_uint(r1);
  float f2 = __uint_as_float(u2 & 0xFFFF0000u);
  float r2 = r1 - f2;
  out[idx]             = (unsigned short)(u1 >> 16);
  out[total + idx]     = (unsigned short)(u2 >> 16);
  out[2 * total + idx] = (unsigned short)(__float_as_uint(r2) >> 16);
}

__global__ __launch_bounds__(256) void k_prep(
    const float* __restrict__ state, const float* __restrict__ task,
    const float* __restrict__ action, float* __restrict__ Cg,
    const float* __restrict__ W1, const float* __restrict__ W2,
    const float* __restrict__ W3, const float* __restrict__ W4,
    const float* __restrict__ W5, const float* __restrict__ W6,
    unsigned short* __restrict__ WS,
    unsigned long long* __restrict__ kpk,
    size_t o11, size_t o12, size_t o21, size_t o22, size_t o31, size_t o32)
{
  int idx = blockIdx.x * 256 + threadIdx.x;
  if (idx < CT_ITEMS) {
    int b = idx / CSL, s = idx - b * CSL;
    v4f v;
    if (s < 256)       v = *((const v4f*)state  + (size_t)b * 256 + s);
    else if (s == 256) v = *((const v4f*)task   + b);
    else               v = *((const v4f*)action + (size_t)b * 64 + (s - 257));
    *((v4f*)Cg + idx) = v;
    return;
  }
  idx -= CT_ITEMS;
  if (idx < E_C11) { split_one(W1, WS + o11, 1024, KCTX, 1312, idx); return; }
  idx -= E_C11;
  if (idx < E_C12) { split_one(W2, WS + o12, 1024, 1024, 1024, idx); return; }
  idx -= E_C12;
  if (idx < E_C21) { split_one(W3, WS + o21,  512, KCTX, 1312, idx); return; }
  idx -= E_C21;
  if (idx < E_C22) { split_one(W4, WS + o22,  512,  512,  512, idx); return; }
  idx -= E_C22;
  if (idx < E_C31) { split_one(W5, WS + o31,  256, KCTX, 1312, idx); return; }
  idx -= E_C31;
  if (idx < E_C32) { split_one(W6, WS + o32,  256,  256,  256, idx); return; }
  idx -= E_C32;
  if (idx < KPK_ITEMS) kpk[idx] = 0ull;
}

// =================== fp64-MFMA GEMM (main chain) — r6 math, dbuf LDS ========
// EPI: 0 = store f64, 2 = row-argmax only, 3 = store f32, 4 = tanh->f32
// ASRC: 0 = A fp32 (any K), 1 = A fp64 (K%16==0)
// D-layout (f64 16x16x4): col = lane&15, row = 4*reg + (lane>>4)
// Double-buffered LDS: one barrier per K-tile (compute buf t || stage buf t+1,
// race-free: barrier at end of t-1 means all waves finished compute(t-1),
// the last reader of buf[(t+1)&1]). MFMA order unchanged -> bit-identical.
#define TM 128
#define TN 64
#define TK 16
#define LRA 130
#define LRB 66

template<int EPI, int ASRC>
__global__ __launch_bounds__(256, 3) void g64m(
    const void* __restrict__ Av, const float* __restrict__ W,
    const float* __restrict__ bias, void* __restrict__ Cv,
    unsigned long long* __restrict__ kpk, int N, int K)
{
  __shared__ __align__(16) double As[2][TK * LRA];
  __shared__ __align__(16) double Ws[2][TK * LRB];

  const int tid  = threadIdx.x;
  const int lane = tid & 63;
  const int wid  = tid >> 6;
  const int wm   = wid >> 1;
  const int wn   = wid & 1;
  const int grp  = lane >> 4;
  const int lid  = lane & 15;
  const int row0 = blockIdx.x * TM;
  const int col0 = blockIdx.y * TN;

  const int lrA = tid >> 1;
  const int lcA = (tid & 1) * 8;
  const int lrW = tid >> 2;
  const int lcW = (tid & 3) * 4;

  const float*  ApF = (const float*)Av  + (size_t)(row0 + lrA) * K;
  const double* ApD = (const double*)Av + (size_t)(row0 + lrA) * K;
  const float*  WpF = W + (size_t)(col0 + lrW) * K;

  double sa[8], sw[4];

  v4d acc[4][2];
  #pragma unroll
  for (int i = 0; i < 4; ++i)
    #pragma unroll
    for (int j = 0; j < 2; ++j) { acc[i][j][0] = 0.0; acc[i][j][1] = 0.0;
                                  acc[i][j][2] = 0.0; acc[i][j][3] = 0.0; }

  const int nt = (K + TK - 1) / TK;

  auto loadA = [&](int k0) {
    const int kb = k0 + lcA;
    if (ASRC == 0) {
      if (kb + 8 <= K) {
        v4f x0 = *(const v4f*)(ApF + kb), x1 = *(const v4f*)(ApF + kb + 4);
        sa[0] = x0.x; sa[1] = x0.y; sa[2] = x0.z; sa[3] = x0.w;
        sa[4] = x1.x; sa[5] = x1.y; sa[6] = x1.z; sa[7] = x1.w;
      } else {
        #pragma unroll
        for (int j = 0; j < 8; ++j) sa[j] = (kb + j < K) ? (double)ApF[kb + j] : 0.0;
      }
    } else {
      const double* p = ApD + kb;
      v2d d0 = *(const v2d*)p,       d1 = *(const v2d*)(p + 2);
      v2d d2 = *(const v2d*)(p + 4), d3 = *(const v2d*)(p + 6);
      sa[0] = d0.x; sa[1] = d0.y; sa[2] = d1.x; sa[3] = d1.y;
      sa[4] = d2.x; sa[5] = d2.y; sa[6] = d3.x; sa[7] = d3.y;
    }
  };
  auto loadW = [&](int k0) {
    const int kb = k0 + lcW;
    if (kb + 4 <= K) {
      v4f w0 = *(const v4f*)(WpF + kb);
      sw[0] = w0.x; sw[1] = w0.y; sw[2] = w0.z; sw[3] = w0.w;
    } else {
      #pragma unroll
      for (int j = 0; j < 4; ++j) sw[j] = (kb + j < K) ? (double)WpF[kb + j] : 0.0;
    }
  };
  auto stage = [&](int buf) {
    #pragma unroll
    for (int j = 0; j < 8; ++j) As[buf][(lcA + j) * LRA + lrA] = sa[j];
    #pragma unroll
    for (int j = 0; j < 4; ++j) Ws[buf][(lcW + j) * LRB + lrW] = sw[j];
  };

  loadA(0); loadW(0);
  stage(0);
  __syncthreads();                 // buf 0 visible to all

  for (int t = 0; t < nt; ++t) {
    const int cb = t & 1;
    if (t + 1 < nt) { loadA((t + 1) * TK); loadW((t + 1) * TK); }
    #pragma unroll
    for (int ks = 0; ks < 4; ++ks) {
      const double* Ar = As[cb] + (ks * 4 + grp) * LRA + wm * 64 + lid;
      const double* Br = Ws[cb] + (ks * 4 + grp) * LRB + wn * 32 + lid;
      double a[4], b[2];
      #pragma unroll
      for (int i = 0; i < 4; ++i) a[i] = Ar[i * 16];
      #pragma unroll
      for (int j = 0; j < 2; ++j) b[j] = Br[j * 16];
      #pragma unroll
      for (int i = 0; i < 4; ++i)
        #pragma unroll
        for (int j = 0; j < 2; ++j)
          acc[i][j] = MFMA64(a[i], b[j], acc[i][j]);
    }
    if (t + 1 < nt) stage(cb ^ 1);   // last reads of this buffer were at t-1,
    __syncthreads();                 // fenced by the barrier below / prior iter
  }

  double bb[2];
  #pragma unroll
  for (int j = 0; j < 2; ++j) bb[j] = (double)bias[col0 + wn * 32 + j * 16 + lid];

  if (EPI == 0) {
    #pragma unroll
    for (int i = 0; i < 4; ++i)
      #pragma unroll
      for (int r = 0; r < 4; ++r) {
        int row = row0 + wm * 64 + i * 16 + r * 4 + grp;
        double* Cp = (double*)Cv + (size_t)row * N + col0 + wn * 32 + lid;
        #pragma unroll
        for (int j = 0; j < 2; ++j) Cp[j * 16] = acc[i][j][r] + bb[j];
      }
  } else if (EPI == 3 || EPI == 4) {
    #pragma unroll
    for (int i = 0; i < 4; ++i)
      #pragma unroll
      for (int r = 0; r < 4; ++r) {
        int row = row0 + wm * 64 + i * 16 + r * 4 + grp;
        float* Cp = (float*)Cv + (size_t)row * N + col0 + wn * 32 + lid;
        #pragma unroll
        for (int j = 0; j < 2; ++j) {
          double o = acc[i][j][r] + bb[j];
          if (EPI == 4) o = tanh(o);
          Cp[j * 16] = (float)o;
        }
      }
  } else {
    #pragma unroll
    for (int i = 0; i < 4; ++i)
      #pragma unroll
      for (int r = 0; r < 4; ++r) {
        int row = row0 + wm * 64 + i * 16 + r * 4 + grp;
        double best = acc[i][0][r] + bb[0];
        int bcol = col0 + wn * 32 + lid;
        {
          double v = acc[i][1][r] + bb[1];
          if (v > best) { best = v; bcol = col0 + wn * 32 + 16 + lid; }
        }
        #pragma unroll
        for (int d = 1; d < 16; d <<= 1) {
          double ov = __shfl_xor(best, d);
          int    oc = __shfl_xor(bcol, d);
          if (ov > best || (ov == best && oc < bcol)) { best = ov; bcol = oc; }
        }
        if (lid == 0) {
          unsigned long long key =
              (f64_ord(best) & ~0xFFFFull) | ((~(unsigned)bcol) & 0xFFFFu);
          atomicMax(&kpk[row], key);
        }
      }
  }
}

// =================== bf16x3 tower GEMM — r13-proven (FROZEN) ================
// ASPLIT: 0 = A is f32 (split in-kernel), 1 = A is pre-split 3-plane bf16
// EPI:    4 = tanh -> store f32;  2 = row-argmax only
// D-layout (bf16 16x16x32): col=lane&15, row=(lane>>4)*4+reg
#define GTM 64
#define GTN 128
#define GTK 32
#define GLR 40

template<int EPI, int ASPLIT>
__global__ __launch_bounds__(256, 2) void g16(
    const void* __restrict__ Av, size_t aplane,
    const unsigned short* __restrict__ WS_,
    const float* __restrict__ bias,
    unsigned short* __restrict__ Hout, size_t hplane,
    unsigned long long* __restrict__ kpk, int N, int K, int KP)
{
  __shared__ __align__(16) unsigned short Al[3][GTM * GLR];
  __shared__ __align__(16) unsigned short Wl[3][GTN * GLR];

  const int tid  = threadIdx.x;
  const int lane = tid & 63;
  const int wid  = tid >> 6;       // wave 0..3 = column group (32 cols each)
  const int grp  = lane >> 4;
  const int lid  = lane & 15;
  const int row0 = blockIdx.x * GTM;
  const int col0 = blockIdx.y * GTN;

  const int arow = tid >> 2, akc = (tid & 3) * 8;    // A loader: 8 k / thread
  const int wrow = tid >> 1, wkc = (tid & 1) * 16;   // W loader: 16 k / thread
  const float*          ApF = (const float*)Av + (size_t)(row0 + arow) * K;
  const unsigned short* ApS = (const unsigned short*)Av + (size_t)(row0 + arow) * K;
  const unsigned short* WpS = WS_ + (size_t)(col0 + wrow) * KP + wkc;
  const size_t wplane = (size_t)N * KP;

  float av[8];
  s16x8 sA[3], sW[3][2];

  f32x4 ah[4][2], am[4][2], al[4][2];
  double sh[4][2][4];
  #pragma unroll
  for (int i = 0; i < 4; ++i)
    #pragma unroll
    for (int j = 0; j < 2; ++j) {
      ah[i][j] = (f32x4)0.f; am[i][j] = (f32x4)0.f; al[i][j] = (f32x4)0.f;
      #pragma unroll
      for (int r = 0; r < 4; ++r) sh[i][j][r] = 0.0;
    }

  const int nt = KP / GTK;

  auto loadA = [&](int kb) {
    if (ASPLIT == 0) {
      #pragma unroll
      for (int q = 0; q < 2; ++q) {
        int k = kb + akc + q * 4;
        if (k + 4 <= K) {
          v4f x = *(const v4f*)(ApF + k);
          av[q*4+0] = x.x; av[q*4+1] = x.y; av[q*4+2] = x.z; av[q*4+3] = x.w;
        } else {
          #pragma unroll
          for (int j = 0; j < 4; ++j) av[q*4+j] = (k + j < K) ? ApF[k + j] : 0.f;
        }
      }
    } else {
      #pragma unroll
      for (int p = 0; p < 3; ++p)
        sA[p] = *(const s16x8*)(ApS + p * aplane + kb + akc);
    }
  };
  auto loadW = [&](int kb) {
    #pragma unroll
    for (int p = 0; p < 3; ++p) {
      const unsigned short* s = WpS + p * wplane + kb;
      sW[p][0] = *(const s16x8*)s;
      sW[p][1] = *(const s16x8*)(s + 8);
    }
  };

  auto split8 = [](const float* v, s16x8& p1, s16x8& p2, s16x8& p3) {
    #pragma unroll
    for (int j = 0; j < 8; ++j) {
      unsigned u1 = __float_as_uint(v[j]);
      float f1 = __uint_as_float(u1 & 0xFFFF0000u);
      float r1 = v[j] - f1;
      unsigned u2 = __float_as_uint(r1);
      float f2 = __uint_as_float(u2 & 0xFFFF0000u);
      float r2 = r1 - f2;
      p1[j] = (short)(u1 >> 16); p2[j] = (short)(u2 >> 16);
      p3[j] = (short)(__float_as_uint(r2) >> 16);
    }
  };

  loadA(0); loadW(0);

  for (int t = 0; t < nt; ++t) {
    __syncthreads();
    if (ASPLIT == 0) {
      s16x8 p1, p2, p3;
      split8(av, p1, p2, p3);
      *(s16x8*)&Al[0][arow * GLR + akc] = p1;
      *(s16x8*)&Al[1][arow * GLR + akc] = p2;
      *(s16x8*)&Al[2][arow * GLR + akc] = p3;
    } else {
      #pragma unroll
      for (int p = 0; p < 3; ++p)
        *(s16x8*)&Al[p][arow * GLR + akc] = sA[p];
    }
    #pragma unroll
    for (int p = 0; p < 3; ++p) {
      *(s16x8*)&Wl[p][wrow * GLR + wkc]     = sW[p][0];
      *(s16x8*)&Wl[p][wrow * GLR + wkc + 8] = sW[p][1];
    }
    if (t + 1 < nt) { loadA((t + 1) * GTK); loadW((t + 1) * GTK); }
    __syncthreads();

    s16x8 b0[2], b1[2], b2[2];
    #pragma unroll
    for (int nf = 0; nf < 2; ++nf) {
      int widx = (wid * 32 + nf * 16 + lid) * GLR + grp * 8;
      b0[nf] = *(const s16x8*)&Wl[0][widx];
      b1[nf] = *(const s16x8*)&Wl[1][widx];
      b2[nf] = *(const s16x8*)&Wl[2][widx];
    }
    #pragma unroll
    for (int mf = 0; mf < 4; ++mf) {
      int aidx = (mf * 16 + lid) * GLR + grp * 8;
      s16x8 a0 = *(const s16x8*)&Al[0][aidx];
      s16x8 a1 = *(const s16x8*)&Al[1][aidx];
      s16x8 a2 = *(const s16x8*)&Al[2][aidx];
      #pragma unroll
      for (int nf = 0; nf < 2; ++nf) {
        ah[mf][nf] = mfma_bf16(a0, b0[nf], ah[mf][nf]);
        am[mf][nf] = mfma_bf16(a0, b1[nf], am[mf][nf]);
        am[mf][nf] = mfma_bf16(a1, b0[nf], am[mf][nf]);
        al[mf][nf] = mfma_bf16(a0, b2[nf], al[mf][nf]);
        al[mf][nf] = mfma_bf16(a1, b1[nf], al[mf][nf]);
        al[mf][nf] = mfma_bf16(a2, b0[nf], al[mf][nf]);
      }
    }
    if ((t & 7) == 7) {
      MFMA_GUARD();
      #pragma unroll
      for (int mf = 0; mf < 4; ++mf)
        #pragma unroll
        for (int nf = 0; nf < 2; ++nf) {
          #pragma unroll
          for (int r = 0; r < 4; ++r) sh[mf][nf][r] += (double)ah[mf][nf][r];
          ah[mf][nf] = (f32x4)0.f;
        }
    }
  }

  MFMA_GUARD();
  #pragma unroll
  for (int mf = 0; mf < 4; ++mf)
    #pragma unroll
    for (int nf = 0; nf < 2; ++nf)
      #pragma unroll
      for (int r = 0; r < 4; ++r) sh[mf][nf][r] += (double)ah[mf][nf][r];

  double bb[2];
  #pragma unroll
  for (int nf = 0; nf < 2; ++nf) bb[nf] = (double)bias[col0 + wid * 32 + nf * 16 + lid];

  if (EPI == 4) {
    #pragma unroll
    for (int mf = 0; mf < 4; ++mf)
      #pragma unroll
      for (int r = 0; r < 4; ++r) {
        int row = row0 + mf * 16 + grp * 4 + r;
        float* Hp = (float*)Hout + (size_t)row * N + col0 + wid * 32 + lid;
        #pragma unroll
        for (int nf = 0; nf < 2; ++nf) {
          double o = sh[mf][nf][r] + (double)am[mf][nf][r] + (double)al[mf][nf][r] + bb[nf];
          Hp[nf * 16] = (float)tanh(o);
        }
      }
  } else {
    #pragma unroll
    for (int mf = 0; mf < 4; ++mf)
      #pragma unroll
      for (int r = 0; r < 4; ++r) {
        int row = row0 + mf * 16 + grp * 4 + r;
        double v0 = sh[mf][0][r] + (double)am[mf][0][r] + (double)al[mf][0][r] + bb[0];
        double v1 = sh[mf][1][r] + (double)am[mf][1][r] + (double)al[mf][1][r] + bb[1];
        double best = v0; int bcol = col0 + wid * 32 + lid;
        if (v1 > best) { best = v1; bcol = col0 + wid * 32 + 16 + lid; }
        #pragma unroll
        for (int d = 1; d < 16; d <<= 1) {
          double ov = __shfl_xor(best, d);
          int    oc = __shfl_xor(bcol, d);
          if (ov > best || (ov == best && oc < bcol)) { best = ov; bcol = oc; }
        }
        if (lid == 0) {
          unsigned long long key =
              (f64_ord(best) & ~0xFFFFull) | ((~(unsigned)bcol) & 0xFFFFu);
          atomicMax(&kpk[row], key);
        }
      }
  }
}

// ---------------- kwta on fp64: exact radix-select of k-th largest ----------
// scan via wave-level __shfl_up (4 barriers/pass; counts exact)
__global__ __launch_bounds__(256) void k_kwta64(
    double* __restrict__ X, int N, const unsigned long long* __restrict__ kpk)
{
  const int row = blockIdx.x;
  const int tid = threadIdx.x;
  const int lane = tid & 63;
  const int wv   = tid >> 6;
  double* x = X + (size_t)row * N;
  __shared__ unsigned long long su[1024];
  __shared__ int hist[256];
  __shared__ int wsum[4];
  __shared__ int s_bin, s_base, s_cnt;

  unsigned long long p = kpk[row];
  int k = (int)((~p) & 0xFFFFull);

  for (int j = tid; j < N; j += 256) su[j] = f64_ord(x[j]);
  __syncthreads();

  unsigned long long uth = 0xFFFFFFFFFFFFFFFFull;   // k==0: damp everything
  if (k > 0) {
    int t = N - k;                 // ascending 0-indexed rank of k-th largest
    unsigned long long prefix = 0;
    for (int shift = 56; shift >= 0; shift -= 8) {
      hist[tid] = 0;
      __syncthreads();
      unsigned long long pm =
          (shift == 56) ? 0ull : ~((1ull << (shift + 8)) - 1ull);
      for (int j = tid; j < N; j += 256) {
        unsigned long long u = su[j];
        if ((u & pm) == prefix) atomicAdd(&hist[(int)((u >> shift) & 255)], 1);
      }
      __syncthreads();
      int h = hist[tid];
      int xsc = h;
      #pragma unroll
      for (int d = 1; d < 64; d <<= 1) {
        int y = __shfl_up(xsc, d, 64);
        if (lane >= d) xsc += y;
      }
      if (lane == 63) wsum[wv] = xsc;
      __syncthreads();
      int add = 0;
      #pragma unroll
      for (int i = 0; i < 3; ++i) if (i < wv) add += wsum[i];
      int incl = xsc + add;
      int excl = incl - h;
      if (h > 0 && t >= excl && t < incl) {
        s_bin = tid; s_base = excl; s_cnt = h;
      }
      __syncthreads();
      prefix |= ((unsigned long long)s_bin) << shift;
      t -= s_base;
      int cnt = s_cnt;
      __syncthreads();
      if (cnt == 1) break;
    }
    uth = prefix;
  }
  __syncthreads();
  for (int j = tid; j < N; j += 256) {
    if (su[j] < uth) x[j] = x[j] / 3.0;
  }
}

// ---------------- launch ----------------
extern "C" void kernel_launch(void* const* d_in, const int* in_sizes, int n_in,
                              void* d_out, int out_size, void* d_ws, size_t ws_size,
                              hipStream_t stream)
{
  const float* state   = (const float*)d_in[0];
  const float* task    = (const float*)d_in[1];
  const float* action  = (const float*)d_in[2];
  const float* W_cx1_1 = (const float*)d_in[3];  const float* b_cx1_1 = (const float*)d_in[4];
  const float* W_cx1_2 = (const float*)d_in[5];  const float* b_cx1_2 = (const float*)d_in[6];
  const float* W_cx2_1 = (const float*)d_in[7];  const float* b_cx2_1 = (const float*)d_in[8];
  const float* W_cx2_2 = (const float*)d_in[9];  const float* b_cx2_2 = (const float*)d_in[10];
  const float* W_cx3_1 = (const float*)d_in[11]; const float* b_cx3_1 = (const float*)d_in[12];
  const float* W_cx3_2 = (const float*)d_in[13]; const float* b_cx3_2 = (const float*)d_in[14];
  const float* W_l1    = (const float*)d_in[15]; const float* b_l1    = (const float*)d_in[16];
  const float* W_l2    = (const float*)d_in[17]; const float* b_l2    = (const float*)d_in[18];
  const float* W_l3    = (const float*)d_in[19]; const float* b_l3    = (const float*)d_in[20];
  const float* W_l4    = (const float*)d_in[21]; const float* b_l4    = (const float*)d_in[22];

  // ---- workspace overlay (peak 218,365,952 B — identical to proven r3-r13) -
  char* wsb = (char*)d_ws;
  double* A1 = (double*)wsb;
  float*  Hf = (float*)wsb;                              // <= 67,108,864 B
  double* A3 = (double*)wsb;
  unsigned short* WS  = (unsigned short*)(wsb + 100663296ULL);
  float*  Cg = (float*)(wsb + 134217728ULL);
  double* A2 = (double*)(wsb + 134217728ULL);
  unsigned long long* kpk = (unsigned long long*)d_out;

  // pre-split W offsets (bf16 elems; each matrix = 3 planes of N*KP)
  const size_t o_c11 = 0;            // 1024x1312
  const size_t o_c12 = 4030464;      // 1024x1024
  const size_t o_c21 = 7176192;      // 512x1312
  const size_t o_c22 = 9191424;      // 512x512
  const size_t o_c31 = 9977856;      // 256x1312
  const size_t o_c32 = 10985472;     // 256x256

  dim3 blk(256);

  // fused prep: ctx concat + all 6 weight splits + kpk zeroing (1 launch)
  k_prep<<<(CT_ITEMS + E_C11 + E_C12 + E_C21 + E_C22 + E_C31 + E_C32 + KPK_ITEMS) / 256,
           blk, 0, stream>>>(state, task, action, Cg,
                             W_cx1_1, W_cx1_2, W_cx2_1, W_cx2_2, W_cx3_1, W_cx3_2,
                             WS, kpk, o_c11, o_c12, o_c21, o_c22, o_c31, o_c32);

  // gate towers (bf16x3; h stored f32; logits split in-kernel) — r13-frozen
  g16<4,0><<<dim3(NB/GTM, 1024/GTN), blk, 0, stream>>>(Cg, 0, WS + o_c11, b_cx1_1,
      (unsigned short*)Hf, 0, nullptr, 1024, KCTX, 1312);
  g16<2,0><<<dim3(NB/GTM, 1024/GTN), blk, 0, stream>>>(Hf, 0, WS + o_c12, b_cx1_2,
      nullptr, 0, kpk, 1024, 1024, 1024);
  g16<4,0><<<dim3(NB/GTM,  512/GTN), blk, 0, stream>>>(Cg, 0, WS + o_c21, b_cx2_1,
      (unsigned short*)Hf, 0, nullptr, 512, KCTX, 1312);
  g16<2,0><<<dim3(NB/GTM,  512/GTN), blk, 0, stream>>>(Hf, 0, WS + o_c22, b_cx2_2,
      nullptr, 0, kpk + NB, 512, 512, 512);
  g16<4,0><<<dim3(NB/GTM,  256/GTN), blk, 0, stream>>>(Cg, 0, WS + o_c31, b_cx3_1,
      (unsigned short*)Hf, 0, nullptr, 256, KCTX, 1312);
  g16<2,0><<<dim3(NB/GTM,  256/GTN), blk, 0, stream>>>(Hf, 0, WS + o_c32, b_cx3_2,
      nullptr, 0, kpk + 2 * NB, 256, 256, 256);

  // main chain, fp64 end to end (decision-exact); dbuf LDS, math unchanged
  g64m<0,0><<<dim3(NB/TM, 1024/TN), blk, 0, stream>>>(Cg, W_l1, b_l1, A1, nullptr, 1024, KCTX);
  k_kwta64<<<NB, blk, 0, stream>>>(A1, 1024, kpk);
  g64m<0,1><<<dim3(NB/TM,  512/TN), blk, 0, stream>>>(A1, W_l2, b_l2, A2, nullptr,  512, 1024);
  k_kwta64<<<NB, blk, 0, stream>>>(A2,  512, kpk + NB);
  g64m<0,1><<<dim3(NB/TM,  256/TN), blk, 0, stream>>>(A2, W_l3, b_l3, A3, nullptr,  256,  512);
  k_kwta64<<<NB, blk, 0, stream>>>(A3,  256, kpk + 2*NB);
  g64m<3,1><<<dim3(NB/TM,  256/TN), blk, 0, stream>>>(A3, W_l4, b_l4, (float*)d_out, nullptr, 256, 256);
}

// Round 15
// 2198.215 us; speedup vs baseline: 1.0712x; 1.0712x over previous
//
#include <hip/hip_runtime.h>
#include <math.h>

typedef float  v4f   __attribute__((ext_vector_type(4)));
typedef double v2d   __attribute__((ext_vector_type(2)));
typedef double v4d   __attribute__((ext_vector_type(4)));
typedef float  f32x4 __attribute__((ext_vector_type(4)));
typedef short  s16x8 __attribute__((ext_vector_type(8)));

#define NB   16384
#define KCTX 1284
#define CSL  (KCTX/4)    // 321 float4 per ctx row

// ---- fp64 MFMA: D[16x16] += A[16x4] * B[4x16], per-wave ----
#if defined(__has_builtin)
#  if __has_builtin(__builtin_amdgcn_mfma_f64_16x16x4f64)
#    define MFMA64(a, b, c) __builtin_amdgcn_mfma_f64_16x16x4f64((a), (b), (c), 0, 0, 0)
#  endif
#endif
#ifndef MFMA64
static __device__ __forceinline__ v4d mfma64_asm(double a, double b, v4d c) {
  asm volatile("v_mfma_f64_16x16x4_f64 %0, %1, %2, %0" : "+v"(c) : "v"(a), "v"(b));
  return c;
}
#  define MFMA64(a, b, c) mfma64_asm((a), (b), (c))
#endif

// ---- bf16 MFMA 16x16x32 (inline asm, volatile; r11/r13-proven) ----
static __device__ __forceinline__ f32x4 mfma_bf16(s16x8 a, s16x8 b, f32x4 c) {
  asm volatile("v_mfma_f32_16x16x32_bf16 %0, %1, %2, %0" : "+v"(c) : "v"(a), "v"(b));
  return c;
}
// MFMA-dst -> VALU-read hazard guard (r11-proven form)
#define MFMA_GUARD() do {                                  \
  __builtin_amdgcn_sched_barrier(0);                       \
  asm volatile("s_nop 7\ns_nop 7\ns_nop 7\ns_nop 7");      \
  __builtin_amdgcn_sched_barrier(0);                       \
} while (0)

__device__ __forceinline__ unsigned long long f64_ord(double f) {
  unsigned long long u = (unsigned long long)__double_as_longlong(f);
  return (u & 0x8000000000000000ull) ? ~u : (u | 0x8000000000000000ull);
}

// ---------------- fused prep: ctx concat + 6 weight splits + kpk zero -------
#define CT_ITEMS  (NB * CSL)          // 5,259,264 float4 slots
#define E_C11     (1024 * 1312)
#define E_C12     (1024 * 1024)
#define E_C21     ( 512 * 1312)
#define E_C22     ( 512 *  512)
#define E_C31     ( 256 * 1312)
#define E_C32     ( 256 *  256)
#define KPK_ITEMS (3 * NB)

static __device__ __forceinline__ void split_one(
    const float* __restrict__ W, unsigned short* __restrict__ out,
    int N, int K, int KP, int idx)
{
  size_t total = (size_t)N * KP;
  int n = idx / KP, k = idx - n * KP;
  float v = (k < K) ? W[(size_t)n * K + k] : 0.f;
  unsigned u1 = __float_as_uint(v);
  float f1 = __uint_as_float(u1 & 0xFFFF0000u);
  float r1 = v - f1;
  unsigned u2 = __float_as_uint(r1);
  float f2 = __uint_as_float(u2 & 0xFFFF0000u);
  float r2 = r1 - f2;
  out[idx]             = (unsigned short)(u1 >> 16);
  out[total + idx]     = (unsigned short)(u2 >> 16);
  out[2 * total + idx] = (unsigned short)(__float_as_uint(r2) >> 16);
}

__global__ __launch_bounds__(256) void k_prep(
    const float* __restrict__ state, const float* __restrict__ task,
    const float* __restrict__ action, float* __restrict__ Cg,
    const float* __restrict__ W1, const float* __restrict__ W2,
    const float* __restrict__ W3, const float* __restrict__ W4,
    const float* __restrict__ W5, const float* __restrict__ W6,
    unsigned short* __restrict__ WS,
    unsigned long long* __restrict__ kpk,
    size_t o11, size_t o12, size_t o21, size_t o22, size_t o31, size_t o32)
{
  int idx = blockIdx.x * 256 + threadIdx.x;
  if (idx < CT_ITEMS) {
    int b = idx / CSL, s = idx - b * CSL;
    v4f v;
    if (s < 256)       v = *((const v4f*)state  + (size_t)b * 256 + s);
    else if (s == 256) v = *((const v4f*)task   + b);
    else               v = *((const v4f*)action + (size_t)b * 64 + (s - 257));
    *((v4f*)Cg + idx) = v;
    return;
  }
  idx -= CT_ITEMS;
  if (idx < E_C11) { split_one(W1, WS + o11, 1024, KCTX, 1312, idx); return; }
  idx -= E_C11;
  if (idx < E_C12) { split_one(W2, WS + o12, 1024, 1024, 1024, idx); return; }
  idx -= E_C12;
  if (idx < E_C21) { split_one(W3, WS + o21,  512, KCTX, 1312, idx); return; }
  idx -= E_C21;
  if (idx < E_C22) { split_one(W4, WS + o22,  512,  512,  512, idx); return; }
  idx -= E_C22;
  if (idx < E_C31) { split_one(W5, WS + o31,  256, KCTX, 1312, idx); return; }
  idx -= E_C31;
  if (idx < E_C32) { split_one(W6, WS + o32,  256,  256,  256, idx); return; }
  idx -= E_C32;
  if (idx < KPK_ITEMS) kpk[idx] = 0ull;
}

// =================== fp64-MFMA GEMM (main chain) — r13-proven single-buffer =
// EPI: 0 = store f64, 2 = row-argmax only, 3 = store f32, 4 = tanh->f32
// ASRC: 0 = A fp32 (any K), 1 = A fp64 (K%16==0)
// D-layout (f64 16x16x4): col = lane&15, row = 4*reg + (lane>>4)
// NOTE r14 lesson: double-buffered LDS (50 KB) dropped occupancy 44->33% and
// MfmaUtil 80->73 — implicit 3-block overlap beats explicit dbuf here.
#define TM 128
#define TN 64
#define TK 16
#define LRA 130
#define LRB 66

template<int EPI, int ASRC>
__global__ __launch_bounds__(256, 3) void g64m(
    const void* __restrict__ Av, const float* __restrict__ W,
    const float* __restrict__ bias, void* __restrict__ Cv,
    unsigned long long* __restrict__ kpk, int N, int K)
{
  __shared__ __align__(16) double As[TK * LRA];
  __shared__ __align__(16) double Ws[TK * LRB];

  const int tid  = threadIdx.x;
  const int lane = tid & 63;
  const int wid  = tid >> 6;
  const int wm   = wid >> 1;
  const int wn   = wid & 1;
  const int grp  = lane >> 4;
  const int lid  = lane & 15;
  const int row0 = blockIdx.x * TM;
  const int col0 = blockIdx.y * TN;

  const int lrA = tid >> 1;
  const int lcA = (tid & 1) * 8;
  const int lrW = tid >> 2;
  const int lcW = (tid & 3) * 4;

  const float*  ApF = (const float*)Av  + (size_t)(row0 + lrA) * K;
  const double* ApD = (const double*)Av + (size_t)(row0 + lrA) * K;
  const float*  WpF = W + (size_t)(col0 + lrW) * K;

  double sa[8], sw[4];

  v4d acc[4][2];
  #pragma unroll
  for (int i = 0; i < 4; ++i)
    #pragma unroll
    for (int j = 0; j < 2; ++j) { acc[i][j][0] = 0.0; acc[i][j][1] = 0.0;
                                  acc[i][j][2] = 0.0; acc[i][j][3] = 0.0; }

  const int nt = (K + TK - 1) / TK;

  auto loadA = [&](int k0) {
    const int kb = k0 + lcA;
    if (ASRC == 0) {
      if (kb + 8 <= K) {
        v4f x0 = *(const v4f*)(ApF + kb), x1 = *(const v4f*)(ApF + kb + 4);
        sa[0] = x0.x; sa[1] = x0.y; sa[2] = x0.z; sa[3] = x0.w;
        sa[4] = x1.x; sa[5] = x1.y; sa[6] = x1.z; sa[7] = x1.w;
      } else {
        #pragma unroll
        for (int j = 0; j < 8; ++j) sa[j] = (kb + j < K) ? (double)ApF[kb + j] : 0.0;
      }
    } else {
      const double* p = ApD + kb;
      v2d d0 = *(const v2d*)p,       d1 = *(const v2d*)(p + 2);
      v2d d2 = *(const v2d*)(p + 4), d3 = *(const v2d*)(p + 6);
      sa[0] = d0.x; sa[1] = d0.y; sa[2] = d1.x; sa[3] = d1.y;
      sa[4] = d2.x; sa[5] = d2.y; sa[6] = d3.x; sa[7] = d3.y;
    }
  };
  auto loadW = [&](int k0) {
    const int kb = k0 + lcW;
    if (kb + 4 <= K) {
      v4f w0 = *(const v4f*)(WpF + kb);
      sw[0] = w0.x; sw[1] = w0.y; sw[2] = w0.z; sw[3] = w0.w;
    } else {
      #pragma unroll
      for (int j = 0; j < 4; ++j) sw[j] = (kb + j < K) ? (double)WpF[kb + j] : 0.0;
    }
  };

  loadA(0); loadW(0);

  for (int t = 0; t < nt; ++t) {
    __syncthreads();
    #pragma unroll
    for (int j = 0; j < 8; ++j) As[(lcA + j) * LRA + lrA] = sa[j];
    #pragma unroll
    for (int j = 0; j < 4; ++j) Ws[(lcW + j) * LRB + lrW] = sw[j];
    if (t + 1 < nt) { loadA((t + 1) * TK); loadW((t + 1) * TK); }
    __syncthreads();
    #pragma unroll
    for (int ks = 0; ks < 4; ++ks) {
      const double* Ar = As + (ks * 4 + grp) * LRA + wm * 64 + lid;
      const double* Br = Ws + (ks * 4 + grp) * LRB + wn * 32 + lid;
      double a[4], b[2];
      #pragma unroll
      for (int i = 0; i < 4; ++i) a[i] = Ar[i * 16];
      #pragma unroll
      for (int j = 0; j < 2; ++j) b[j] = Br[j * 16];
      #pragma unroll
      for (int i = 0; i < 4; ++i)
        #pragma unroll
        for (int j = 0; j < 2; ++j)
          acc[i][j] = MFMA64(a[i], b[j], acc[i][j]);
    }
  }

  double bb[2];
  #pragma unroll
  for (int j = 0; j < 2; ++j) bb[j] = (double)bias[col0 + wn * 32 + j * 16 + lid];

  if (EPI == 0) {
    #pragma unroll
    for (int i = 0; i < 4; ++i)
      #pragma unroll
      for (int r = 0; r < 4; ++r) {
        int row = row0 + wm * 64 + i * 16 + r * 4 + grp;
        double* Cp = (double*)Cv + (size_t)row * N + col0 + wn * 32 + lid;
        #pragma unroll
        for (int j = 0; j < 2; ++j) Cp[j * 16] = acc[i][j][r] + bb[j];
      }
  } else if (EPI == 3 || EPI == 4) {
    #pragma unroll
    for (int i = 0; i < 4; ++i)
      #pragma unroll
      for (int r = 0; r < 4; ++r) {
        int row = row0 + wm * 64 + i * 16 + r * 4 + grp;
        float* Cp = (float*)Cv + (size_t)row * N + col0 + wn * 32 + lid;
        #pragma unroll
        for (int j = 0; j < 2; ++j) {
          double o = acc[i][j][r] + bb[j];
          if (EPI == 4) o = tanh(o);
          Cp[j * 16] = (float)o;
        }
      }
  } else {
    #pragma unroll
    for (int i = 0; i < 4; ++i)
      #pragma unroll
      for (int r = 0; r < 4; ++r) {
        int row = row0 + wm * 64 + i * 16 + r * 4 + grp;
        double best = acc[i][0][r] + bb[0];
        int bcol = col0 + wn * 32 + lid;
        {
          double v = acc[i][1][r] + bb[1];
          if (v > best) { best = v; bcol = col0 + wn * 32 + 16 + lid; }
        }
        #pragma unroll
        for (int d = 1; d < 16; d <<= 1) {
          double ov = __shfl_xor(best, d);
          int    oc = __shfl_xor(bcol, d);
          if (ov > best || (ov == best && oc < bcol)) { best = ov; bcol = oc; }
        }
        if (lid == 0) {
          unsigned long long key =
              (f64_ord(best) & ~0xFFFFull) | ((~(unsigned)bcol) & 0xFFFFu);
          atomicMax(&kpk[row], key);
        }
      }
  }
}

// =================== bf16x3 tower GEMM — r13-proven (FROZEN) ================
#define GTM 64
#define GTN 128
#define GTK 32
#define GLR 40

template<int EPI, int ASPLIT>
__global__ __launch_bounds__(256, 2) void g16(
    const void* __restrict__ Av, size_t aplane,
    const unsigned short* __restrict__ WS_,
    const float* __restrict__ bias,
    unsigned short* __restrict__ Hout, size_t hplane,
    unsigned long long* __restrict__ kpk, int N, int K, int KP)
{
  __shared__ __align__(16) unsigned short Al[3][GTM * GLR];
  __shared__ __align__(16) unsigned short Wl[3][GTN * GLR];

  const int tid  = threadIdx.x;
  const int lane = tid & 63;
  const int wid  = tid >> 6;       // wave 0..3 = column group (32 cols each)
  const int grp  = lane >> 4;
  const int lid  = lane & 15;
  const int row0 = blockIdx.x * GTM;
  const int col0 = blockIdx.y * GTN;

  const int arow = tid >> 2, akc = (tid & 3) * 8;    // A loader: 8 k / thread
  const int wrow = tid >> 1, wkc = (tid & 1) * 16;   // W loader: 16 k / thread
  const float*          ApF = (const float*)Av + (size_t)(row0 + arow) * K;
  const unsigned short* ApS = (const unsigned short*)Av + (size_t)(row0 + arow) * K;
  const unsigned short* WpS = WS_ + (size_t)(col0 + wrow) * KP + wkc;
  const size_t wplane = (size_t)N * KP;

  float av[8];
  s16x8 sA[3], sW[3][2];

  f32x4 ah[4][2], am[4][2], al[4][2];
  double sh[4][2][4];
  #pragma unroll
  for (int i = 0; i < 4; ++i)
    #pragma unroll
    for (int j = 0; j < 2; ++j) {
      ah[i][j] = (f32x4)0.f; am[i][j] = (f32x4)0.f; al[i][j] = (f32x4)0.f;
      #pragma unroll
      for (int r = 0; r < 4; ++r) sh[i][j][r] = 0.0;
    }

  const int nt = KP / GTK;

  auto loadA = [&](int kb) {
    if (ASPLIT == 0) {
      #pragma unroll
      for (int q = 0; q < 2; ++q) {
        int k = kb + akc + q * 4;
        if (k + 4 <= K) {
          v4f x = *(const v4f*)(ApF + k);
          av[q*4+0] = x.x; av[q*4+1] = x.y; av[q*4+2] = x.z; av[q*4+3] = x.w;
        } else {
          #pragma unroll
          for (int j = 0; j < 4; ++j) av[q*4+j] = (k + j < K) ? ApF[k + j] : 0.f;
        }
      }
    } else {
      #pragma unroll
      for (int p = 0; p < 3; ++p)
        sA[p] = *(const s16x8*)(ApS + p * aplane + kb + akc);
    }
  };
  auto loadW = [&](int kb) {
    #pragma unroll
    for (int p = 0; p < 3; ++p) {
      const unsigned short* s = WpS + p * wplane + kb;
      sW[p][0] = *(const s16x8*)s;
      sW[p][1] = *(const s16x8*)(s + 8);
    }
  };

  auto split8 = [](const float* v, s16x8& p1, s16x8& p2, s16x8& p3) {
    #pragma unroll
    for (int j = 0; j < 8; ++j) {
      unsigned u1 = __float_as_uint(v[j]);
      float f1 = __uint_as_float(u1 & 0xFFFF0000u);
      float r1 = v[j] - f1;
      unsigned u2 = __float_as_uint(r1);
      float f2 = __uint_as_float(u2 & 0xFFFF0000u);
      float r2 = r1 - f2;
      p1[j] = (short)(u1 >> 16); p2[j] = (short)(u2 >> 16);
      p3[j] = (short)(__float_as_uint(r2) >> 16);
    }
  };

  loadA(0); loadW(0);

  for (int t = 0; t < nt; ++t) {
    __syncthreads();
    if (ASPLIT == 0) {
      s16x8 p1, p2, p3;
      split8(av, p1, p2, p3);
      *(s16x8*)&Al[0][arow * GLR + akc] = p1;
      *(s16x8*)&Al[1][arow * GLR + akc] = p2;
      *(s16x8*)&Al[2][arow * GLR + akc] = p3;
    } else {
      #pragma unroll
      for (int p = 0; p < 3; ++p)
        *(s16x8*)&Al[p][arow * GLR + akc] = sA[p];
    }
    #pragma unroll
    for (int p = 0; p < 3; ++p) {
      *(s16x8*)&Wl[p][wrow * GLR + wkc]     = sW[p][0];
      *(s16x8*)&Wl[p][wrow * GLR + wkc + 8] = sW[p][1];
    }
    if (t + 1 < nt) { loadA((t + 1) * GTK); loadW((t + 1) * GTK); }
    __syncthreads();

    s16x8 b0[2], b1[2], b2[2];
    #pragma unroll
    for (int nf = 0; nf < 2; ++nf) {
      int widx = (wid * 32 + nf * 16 + lid) * GLR + grp * 8;
      b0[nf] = *(const s16x8*)&Wl[0][widx];
      b1[nf] = *(const s16x8*)&Wl[1][widx];
      b2[nf] = *(const s16x8*)&Wl[2][widx];
    }
    #pragma unroll
    for (int mf = 0; mf < 4; ++mf) {
      int aidx = (mf * 16 + lid) * GLR + grp * 8;
      s16x8 a0 = *(const s16x8*)&Al[0][aidx];
      s16x8 a1 = *(const s16x8*)&Al[1][aidx];
      s16x8 a2 = *(const s16x8*)&Al[2][aidx];
      #pragma unroll
      for (int nf = 0; nf < 2; ++nf) {
        ah[mf][nf] = mfma_bf16(a0, b0[nf], ah[mf][nf]);
        am[mf][nf] = mfma_bf16(a0, b1[nf], am[mf][nf]);
        am[mf][nf] = mfma_bf16(a1, b0[nf], am[mf][nf]);
        al[mf][nf] = mfma_bf16(a0, b2[nf], al[mf][nf]);
        al[mf][nf] = mfma_bf16(a1, b1[nf], al[mf][nf]);
        al[mf][nf] = mfma_bf16(a2, b0[nf], al[mf][nf]);
      }
    }
    if ((t & 7) == 7) {
      MFMA_GUARD();
      #pragma unroll
      for (int mf = 0; mf < 4; ++mf)
        #pragma unroll
        for (int nf = 0; nf < 2; ++nf) {
          #pragma unroll
          for (int r = 0; r < 4; ++r) sh[mf][nf][r] += (double)ah[mf][nf][r];
          ah[mf][nf] = (f32x4)0.f;
        }
    }
  }

  MFMA_GUARD();
  #pragma unroll
  for (int mf = 0; mf < 4; ++mf)
    #pragma unroll
    for (int nf = 0; nf < 2; ++nf)
      #pragma unroll
      for (int r = 0; r < 4; ++r) sh[mf][nf][r] += (double)ah[mf][nf][r];

  double bb[2];
  #pragma unroll
  for (int nf = 0; nf < 2; ++nf) bb[nf] = (double)bias[col0 + wid * 32 + nf * 16 + lid];

  if (EPI == 4) {
    #pragma unroll
    for (int mf = 0; mf < 4; ++mf)
      #pragma unroll
      for (int r = 0; r < 4; ++r) {
        int row = row0 + mf * 16 + grp * 4 + r;
        float* Hp = (float*)Hout + (size_t)row * N + col0 + wid * 32 + lid;
        #pragma unroll
        for (int nf = 0; nf < 2; ++nf) {
          double o = sh[mf][nf][r] + (double)am[mf][nf][r] + (double)al[mf][nf][r] + bb[nf];
          Hp[nf * 16] = (float)tanh(o);
        }
      }
  } else {
    #pragma unroll
    for (int mf = 0; mf < 4; ++mf)
      #pragma unroll
      for (int r = 0; r < 4; ++r) {
        int row = row0 + mf * 16 + grp * 4 + r;
        double v0 = sh[mf][0][r] + (double)am[mf][0][r] + (double)al[mf][0][r] + bb[0];
        double v1 = sh[mf][1][r] + (double)am[mf][1][r] + (double)al[mf][1][r] + bb[1];
        double best = v0; int bcol = col0 + wid * 32 + lid;
        if (v1 > best) { best = v1; bcol = col0 + wid * 32 + 16 + lid; }
        #pragma unroll
        for (int d = 1; d < 16; d <<= 1) {
          double ov = __shfl_xor(best, d);
          int    oc = __shfl_xor(bcol, d);
          if (ov > best || (ov == best && oc < bcol)) { best = ov; bcol = oc; }
        }
        if (lid == 0) {
          unsigned long long key =
              (f64_ord(best) & ~0xFFFFull) | ((~(unsigned)bcol) & 0xFFFFu);
          atomicMax(&kpk[row], key);
        }
      }
  }
}

// ---------------- kwta on fp64: exact radix-select of k-th largest ----------
__global__ __launch_bounds__(256) void k_kwta64(
    double* __restrict__ X, int N, const unsigned long long* __restrict__ kpk)
{
  const int row = blockIdx.x;
  const int tid = threadIdx.x;
  const int lane = tid & 63;
  const int wv   = tid >> 6;
  double* x = X + (size_t)row * N;
  __shared__ unsigned long long su[1024];
  __shared__ int hist[256];
  __shared__ int wsum[4];
  __shared__ int s_bin, s_base, s_cnt;

  unsigned long long p = kpk[row];
  int k = (int)((~p) & 0xFFFFull);

  for (int j = tid; j < N; j += 256) su[j] = f64_ord(x[j]);
  __syncthreads();

  unsigned long long uth = 0xFFFFFFFFFFFFFFFFull;   // k==0: damp everything
  if (k > 0) {
    int t = N - k;                 // ascending 0-indexed rank of k-th largest
    unsigned long long prefix = 0;
    for (int shift = 56; shift >= 0; shift -= 8) {
      hist[tid] = 0;
      __syncthreads();
      unsigned long long pm =
          (shift == 56) ? 0ull : ~((1ull << (shift + 8)) - 1ull);
      for (int j = tid; j < N; j += 256) {
        unsigned long long u = su[j];
        if ((u & pm) == prefix) atomicAdd(&hist[(int)((u >> shift) & 255)], 1);
      }
      __syncthreads();
      int h = hist[tid];
      int xsc = h;
      #pragma unroll
      for (int d = 1; d < 64; d <<= 1) {
        int y = __shfl_up(xsc, d, 64);
        if (lane >= d) xsc += y;
      }
      if (lane == 63) wsum[wv] = xsc;
      __syncthreads();
      int add = 0;
      #pragma unroll
      for (int i = 0; i < 3; ++i) if (i < wv) add += wsum[i];
      int incl = xsc + add;
      int excl = incl - h;
      if (h > 0 && t >= excl && t < incl) {
        s_bin = tid; s_base = excl; s_cnt = h;
      }
      __syncthreads();
      prefix |= ((unsigned long long)s_bin) << shift;
      t -= s_base;
      int cnt = s_cnt;
      __syncthreads();
      if (cnt == 1) break;
    }
    uth = prefix;
  }
  __syncthreads();
  for (int j = tid; j < N; j += 256) {
    if (su[j] < uth) x[j] = x[j] / 3.0;
  }
}

// ---------------- launch ----------------
extern "C" void kernel_launch(void* const* d_in, const int* in_sizes, int n_in,
                              void* d_out, int out_size, void* d_ws, size_t ws_size,
                              hipStream_t stream)
{
  const float* state   = (const float*)d_in[0];
  const float* task    = (const float*)d_in[1];
  const float* action  = (const float*)d_in[2];
  const float* W_cx1_1 = (const float*)d_in[3];  const float* b_cx1_1 = (const float*)d_in[4];
  const float* W_cx1_2 = (const float*)d_in[5];  const float* b_cx1_2 = (const float*)d_in[6];
  const float* W_cx2_1 = (const float*)d_in[7];  const float* b_cx2_1 = (const float*)d_in[8];
  const float* W_cx2_2 = (const float*)d_in[9];  const float* b_cx2_2 = (const float*)d_in[10];
  const float* W_cx3_1 = (const float*)d_in[11]; const float* b_cx3_1 = (const float*)d_in[12];
  const float* W_cx3_2 = (const float*)d_in[13]; const float* b_cx3_2 = (const float*)d_in[14];
  const float* W_l1    = (const float*)d_in[15]; const float* b_l1    = (const float*)d_in[16];
  const float* W_l2    = (const float*)d_in[17]; const float* b_l2    = (const float*)d_in[18];
  const float* W_l3    = (const float*)d_in[19]; const float* b_l3    = (const float*)d_in[20];
  const float* W_l4    = (const float*)d_in[21]; const float* b_l4    = (const float*)d_in[22];

  // ---- workspace overlay (peak 218,365,952 B — identical to proven r3-r13) -
  char* wsb = (char*)d_ws;
  double* A1 = (double*)wsb;
  float*  Hf = (float*)wsb;                              // <= 67,108,864 B
  double* A3 = (double*)wsb;
  unsigned short* WS  = (unsigned short*)(wsb + 100663296ULL);
  float*  Cg = (float*)(wsb + 134217728ULL);
  double* A2 = (double*)(wsb + 134217728ULL);
  unsigned long long* kpk = (unsigned long long*)d_out;

  // pre-split W offsets (bf16 elems; each matrix = 3 planes of N*KP)
  const size_t o_c11 = 0;            // 1024x1312
  const size_t o_c12 = 4030464;      // 1024x1024
  const size_t o_c21 = 7176192;      // 512x1312
  const size_t o_c22 = 9191424;      // 512x512
  const size_t o_c31 = 9977856;      // 256x1312
  const size_t o_c32 = 10985472;     // 256x256

  dim3 blk(256);

  // fused prep: ctx concat + all 6 weight splits + kpk zeroing (1 launch)
  k_prep<<<(CT_ITEMS + E_C11 + E_C12 + E_C21 + E_C22 + E_C31 + E_C32 + KPK_ITEMS) / 256,
           blk, 0, stream>>>(state, task, action, Cg,
                             W_cx1_1, W_cx1_2, W_cx2_1, W_cx2_2, W_cx3_1, W_cx3_2,
                             WS, kpk, o_c11, o_c12, o_c21, o_c22, o_c31, o_c32);

  // gate towers (bf16x3; h stored f32; logits split in-kernel) — r13-frozen
  g16<4,0><<<dim3(NB/GTM, 1024/GTN), blk, 0, stream>>>(Cg, 0, WS + o_c11, b_cx1_1,
      (unsigned short*)Hf, 0, nullptr, 1024, KCTX, 1312);
  g16<2,0><<<dim3(NB/GTM, 1024/GTN), blk, 0, stream>>>(Hf, 0, WS + o_c12, b_cx1_2,
      nullptr, 0, kpk, 1024, 1024, 1024);
  g16<4,0><<<dim3(NB/GTM,  512/GTN), blk, 0, stream>>>(Cg, 0, WS + o_c21, b_cx2_1,
      (unsigned short*)Hf, 0, nullptr, 512, KCTX, 1312);
  g16<2,0><<<dim3(NB/GTM,  512/GTN), blk, 0, stream>>>(Hf, 0, WS + o_c22, b_cx2_2,
      nullptr, 0, kpk + NB, 512, 512, 512);
  g16<4,0><<<dim3(NB/GTM,  256/GTN), blk, 0, stream>>>(Cg, 0, WS + o_c31, b_cx3_1,
      (unsigned short*)Hf, 0, nullptr, 256, KCTX, 1312);
  g16<2,0><<<dim3(NB/GTM,  256/GTN), blk, 0, stream>>>(Hf, 0, WS + o_c32, b_cx3_2,
      nullptr, 0, kpk + 2 * NB, 256, 256, 256);

  // main chain, fp64 end to end (decision-exact) — r13 single-buffer form
  g64m<0,0><<<dim3(NB/TM, 1024/TN), blk, 0, stream>>>(Cg, W_l1, b_l1, A1, nullptr, 1024, KCTX);
  k_kwta64<<<NB, blk, 0, stream>>>(A1, 1024, kpk);
  g64m<0,1><<<dim3(NB/TM,  512/TN), blk, 0, stream>>>(A1, W_l2, b_l2, A2, nullptr,  512, 1024);
  k_kwta64<<<NB, blk, 0, stream>>>(A2,  512, kpk + NB);
  g64m<0,1><<<dim3(NB/TM,  256/TN), blk, 0, stream>>>(A2, W_l3, b_l3, A3, nullptr,  256,  512);
  k_kwta64<<<NB, blk, 0, stream>>>(A3,  256, kpk + 2*NB);
  g64m<3,1><<<dim3(NB/TM,  256/TN), blk, 0, stream>>>(A3, W_l4, b_l4, (float*)d_out, nullptr, 256, 256);
}